// Round 1
// baseline (2484.359 us; speedup 1.0000x reference)
//
#include <hip/hip_runtime.h>
#include <math.h>

// Problem constants (B=2, S=2048 -> N=4096 tokens)
#define NTOK 4096
#define DDIM 512
#define HDIM 2048
#define NEXP 16

// Workspace layout (bytes). Total ~81 MB.
#define WS_COUNTS   0            // 16 ints
#define WS_OFFSETS  256          // 17 ints
#define WS_EPOS     512          // NTOK*2 ints (packed expert<<16 | pos)
#define WS_TOKLIST  65536        // NEXP*NTOK ints
#define WS_WLIST    327680       // NEXP*NTOK floats
#define WS_HBUF     1048576      // 2*NTOK * HDIM floats = 64 MB
#define WS_YBUF     68157440     // 2*NTOK * DDIM floats = 16 MB

__global__ void zero_counts_kernel(int* __restrict__ counts) {
    if (threadIdx.x < NEXP) counts[threadIdx.x] = 0;
}

// One block = 16 tokens; thread (tl, e) computes logit[token tl][expert e].
__global__ __launch_bounds__(256) void gating_kernel(
    const float* __restrict__ x, const float* __restrict__ Wg,
    const float* __restrict__ bg, int* __restrict__ counts,
    int* __restrict__ tok_list, float* __restrict__ w_list,
    int* __restrict__ epos)
{
    const int tid = threadIdx.x;
    const int tl = tid >> 4;      // token within block, 0..15
    const int e  = tid & 15;      // expert, 0..15
    const int t  = blockIdx.x * 16 + tl;
    const float* xr = x + (size_t)t * DDIM;

    float a0 = 0.f, a1 = 0.f, a2 = 0.f, a3 = 0.f;
    for (int d = 0; d < DDIM; d += 4) {
        a0 = fmaf(xr[d + 0], Wg[(d + 0) * NEXP + e], a0);
        a1 = fmaf(xr[d + 1], Wg[(d + 1) * NEXP + e], a1);
        a2 = fmaf(xr[d + 2], Wg[(d + 2) * NEXP + e], a2);
        a3 = fmaf(xr[d + 3], Wg[(d + 3) * NEXP + e], a3);
    }
    const float logit = (a0 + a1) + (a2 + a3) + bg[e];

    __shared__ float ls[16][16];
    ls[tl][e] = logit;
    __syncthreads();

    if (e == 0) {
        // softmax denom + top-2 over 16 logits (strict > keeps lowest index
        // on ties, matching lax.top_k; raw probs, NOT renormalized)
        float m = -1e30f;
        #pragma unroll
        for (int j = 0; j < NEXP; ++j) m = fmaxf(m, ls[tl][j]);
        float s = 0.f;
        #pragma unroll
        for (int j = 0; j < NEXP; ++j) s += __expf(ls[tl][j] - m);
        int i0 = 0; float v0 = -1e30f;
        #pragma unroll
        for (int j = 0; j < NEXP; ++j) {
            if (ls[tl][j] > v0) { v0 = ls[tl][j]; i0 = j; }
        }
        int i1 = -1; float v1 = -1e30f;
        #pragma unroll
        for (int j = 0; j < NEXP; ++j) {
            if (j != i0 && ls[tl][j] > v1) { v1 = ls[tl][j]; i1 = j; }
        }
        const float w0 = __expf(v0 - m) / s;
        const float w1 = __expf(v1 - m) / s;

        int p0 = atomicAdd(&counts[i0], 1);
        tok_list[i0 * NTOK + p0] = t;
        w_list[i0 * NTOK + p0] = w0;
        epos[t * 2 + 0] = (i0 << 16) | p0;

        int p1 = atomicAdd(&counts[i1], 1);
        tok_list[i1 * NTOK + p1] = t;
        w_list[i1 * NTOK + p1] = w1;
        epos[t * 2 + 1] = (i1 << 16) | p1;
    }
}

__global__ void scan_kernel(const int* __restrict__ counts, int* __restrict__ offsets) {
    if (threadIdx.x == 0 && blockIdx.x == 0) {
        int s = 0;
        for (int e = 0; e < NEXP; ++e) { offsets[e] = s; s += counts[e]; }
        offsets[NEXP] = s;
    }
}

// GEMM1: per expert e, h = relu(X_gathered[Me x 512] @ W1[e][512 x 2048] + b1[e])
// Tile 128x64, BK=16, 256 threads, 8x4 acc/thread.
__global__ __launch_bounds__(256) void gemm1_kernel(
    const float* __restrict__ x, const int* __restrict__ tok_list,
    const int* __restrict__ counts, const int* __restrict__ offsets,
    const float* __restrict__ W1, const float* __restrict__ b1,
    float* __restrict__ hbuf)
{
    const int e  = blockIdx.z;
    const int Me = counts[e];
    const int m0 = blockIdx.x * 128;
    if (m0 >= Me) return;
    const int n0 = blockIdx.y * 64;
    const int tid = threadIdx.x;

    __shared__ float As[16][132];   // k-major, pad 128->132 (2-way max, free)
    __shared__ float Bs[16][64];

    const int lm = tid >> 2;             // 0..63 : A row within tile
    const int kk = (tid & 3) << 2;       // 0,4,8,12 : A k group
    const int kB = tid >> 4;             // 0..15 : B row (k)
    const int nB = (tid & 15) << 2;      // 0..60 : B col group

    const int rA1 = m0 + lm;
    const int rA2 = rA1 + 64;
    const int tok1 = tok_list[e * NTOK + min(rA1, Me - 1)];
    const int tok2 = tok_list[e * NTOK + min(rA2, Me - 1)];
    const float* xr1 = x + (size_t)tok1 * DDIM + kk;
    const float* xr2 = x + (size_t)tok2 * DDIM + kk;
    const float* Wp = W1 + (size_t)e * DDIM * HDIM + (size_t)kB * HDIM + n0 + nB;

    const int ty = tid >> 4;   // 0..15 -> rows ty*8..+7
    const int tx = tid & 15;   // 0..15 -> cols tx*4..+3

    float c[8][4];
    #pragma unroll
    for (int i = 0; i < 8; ++i)
        #pragma unroll
        for (int j = 0; j < 4; ++j) c[i][j] = 0.f;

    for (int k0 = 0; k0 < DDIM; k0 += 16) {
        const float4 a1 = *(const float4*)(xr1 + k0);
        const float4 a2 = *(const float4*)(xr2 + k0);
        const float4 b4 = *(const float4*)(Wp + (size_t)k0 * HDIM);
        As[kk + 0][lm] = a1.x; As[kk + 1][lm] = a1.y;
        As[kk + 2][lm] = a1.z; As[kk + 3][lm] = a1.w;
        As[kk + 0][lm + 64] = a2.x; As[kk + 1][lm + 64] = a2.y;
        As[kk + 2][lm + 64] = a2.z; As[kk + 3][lm + 64] = a2.w;
        *(float4*)&Bs[kB][nB] = b4;
        __syncthreads();
        #pragma unroll
        for (int k = 0; k < 16; ++k) {
            const float4 av0 = *(const float4*)&As[k][ty * 8];
            const float4 av1 = *(const float4*)&As[k][ty * 8 + 4];
            const float4 bv  = *(const float4*)&Bs[k][tx * 4];
            const float ar[8] = {av0.x, av0.y, av0.z, av0.w, av1.x, av1.y, av1.z, av1.w};
            const float br[4] = {bv.x, bv.y, bv.z, bv.w};
            #pragma unroll
            for (int i = 0; i < 8; ++i)
                #pragma unroll
                for (int j = 0; j < 4; ++j)
                    c[i][j] = fmaf(ar[i], br[j], c[i][j]);
        }
        __syncthreads();
    }

    const int aoff = offsets[e];
    #pragma unroll
    for (int i = 0; i < 8; ++i) {
        const int m = m0 + ty * 8 + i;
        if (m < Me) {
            const int n = n0 + tx * 4;
            float4 v;
            v.x = fmaxf(c[i][0] + b1[e * HDIM + n + 0], 0.f);
            v.y = fmaxf(c[i][1] + b1[e * HDIM + n + 1], 0.f);
            v.z = fmaxf(c[i][2] + b1[e * HDIM + n + 2], 0.f);
            v.w = fmaxf(c[i][3] + b1[e * HDIM + n + 3], 0.f);
            *(float4*)&hbuf[(size_t)(aoff + m) * HDIM + n] = v;
        }
    }
}

// GEMM2: y_slot = w * (h[Me x 2048] @ W2[e][2048 x 512] + b2[e])
__global__ __launch_bounds__(256) void gemm2_kernel(
    const float* __restrict__ hbuf, const int* __restrict__ tok_list,
    const float* __restrict__ w_list, const int* __restrict__ counts,
    const int* __restrict__ offsets, const float* __restrict__ W2,
    const float* __restrict__ b2, float* __restrict__ ybuf)
{
    const int e  = blockIdx.z;
    const int Me = counts[e];
    const int m0 = blockIdx.x * 128;
    if (m0 >= Me) return;
    const int n0 = blockIdx.y * 64;
    const int tid = threadIdx.x;
    const int aoff = offsets[e];

    __shared__ float As[16][132];
    __shared__ float Bs[16][64];

    const int lm = tid >> 2;
    const int kk = (tid & 3) << 2;
    const int kB = tid >> 4;
    const int nB = (tid & 15) << 2;

    const int rA1 = aoff + min(m0 + lm, Me - 1);
    const int rA2 = aoff + min(m0 + lm + 64, Me - 1);
    const float* hr1 = hbuf + (size_t)rA1 * HDIM + kk;
    const float* hr2 = hbuf + (size_t)rA2 * HDIM + kk;
    const float* Wp = W2 + (size_t)e * HDIM * DDIM + (size_t)kB * DDIM + n0 + nB;

    const int ty = tid >> 4;
    const int tx = tid & 15;

    float c[8][4];
    #pragma unroll
    for (int i = 0; i < 8; ++i)
        #pragma unroll
        for (int j = 0; j < 4; ++j) c[i][j] = 0.f;

    for (int k0 = 0; k0 < HDIM; k0 += 16) {
        const float4 a1 = *(const float4*)(hr1 + k0);
        const float4 a2 = *(const float4*)(hr2 + k0);
        const float4 b4 = *(const float4*)(Wp + (size_t)k0 * DDIM);
        As[kk + 0][lm] = a1.x; As[kk + 1][lm] = a1.y;
        As[kk + 2][lm] = a1.z; As[kk + 3][lm] = a1.w;
        As[kk + 0][lm + 64] = a2.x; As[kk + 1][lm + 64] = a2.y;
        As[kk + 2][lm + 64] = a2.z; As[kk + 3][lm + 64] = a2.w;
        *(float4*)&Bs[kB][nB] = b4;
        __syncthreads();
        #pragma unroll
        for (int k = 0; k < 16; ++k) {
            const float4 av0 = *(const float4*)&As[k][ty * 8];
            const float4 av1 = *(const float4*)&As[k][ty * 8 + 4];
            const float4 bv  = *(const float4*)&Bs[k][tx * 4];
            const float ar[8] = {av0.x, av0.y, av0.z, av0.w, av1.x, av1.y, av1.z, av1.w};
            const float br[4] = {bv.x, bv.y, bv.z, bv.w};
            #pragma unroll
            for (int i = 0; i < 8; ++i)
                #pragma unroll
                for (int j = 0; j < 4; ++j)
                    c[i][j] = fmaf(ar[i], br[j], c[i][j]);
        }
        __syncthreads();
    }

    #pragma unroll
    for (int i = 0; i < 8; ++i) {
        const int m = m0 + ty * 8 + i;
        if (m < Me) {
            const float w = w_list[e * NTOK + m];
            const int n = n0 + tx * 4;
            float4 v;
            v.x = w * (c[i][0] + b2[e * DDIM + n + 0]);
            v.y = w * (c[i][1] + b2[e * DDIM + n + 1]);
            v.z = w * (c[i][2] + b2[e * DDIM + n + 2]);
            v.w = w * (c[i][3] + b2[e * DDIM + n + 3]);
            *(float4*)&ybuf[(size_t)(aoff + m) * DDIM + n] = v;
        }
    }
}

// out = LayerNorm(x + y_slot0 + y_slot1) * gamma + beta; one wave per token.
__global__ __launch_bounds__(256) void ln_kernel(
    const float* __restrict__ x, const float* __restrict__ ybuf,
    const int* __restrict__ epos, const int* __restrict__ offsets,
    const float* __restrict__ gamma, const float* __restrict__ beta,
    float* __restrict__ out)
{
    const int t = blockIdx.x * 4 + (threadIdx.x >> 6);
    const int lane = threadIdx.x & 63;
    if (t >= NTOK) return;

    const int p0 = epos[2 * t + 0];
    const int p1 = epos[2 * t + 1];
    const size_t r0 = (size_t)(offsets[p0 >> 16] + (p0 & 0xFFFF));
    const size_t r1 = (size_t)(offsets[p1 >> 16] + (p1 & 0xFFFF));

    float v[8];
    float s = 0.f;
    #pragma unroll
    for (int i = 0; i < 8; ++i) {
        const int d = lane + 64 * i;
        v[i] = x[(size_t)t * DDIM + d] + ybuf[r0 * DDIM + d] + ybuf[r1 * DDIM + d];
        s += v[i];
    }
    #pragma unroll
    for (int o = 32; o > 0; o >>= 1) s += __shfl_xor(s, o, 64);
    const float mu = s * (1.f / DDIM);
    float q = 0.f;
    #pragma unroll
    for (int i = 0; i < 8; ++i) { const float d_ = v[i] - mu; q = fmaf(d_, d_, q); }
    #pragma unroll
    for (int o = 32; o > 0; o >>= 1) q += __shfl_xor(q, o, 64);
    const float rstd = rsqrtf(q * (1.f / DDIM) + 1e-5f);
    #pragma unroll
    for (int i = 0; i < 8; ++i) {
        const int d = lane + 64 * i;
        out[(size_t)t * DDIM + d] = (v[i] - mu) * rstd * gamma[d] + beta[d];
    }
}

extern "C" void kernel_launch(void* const* d_in, const int* in_sizes, int n_in,
                              void* d_out, int out_size, void* d_ws, size_t ws_size,
                              hipStream_t stream) {
    const float* x     = (const float*)d_in[0];
    const float* Wg    = (const float*)d_in[1];
    const float* bg    = (const float*)d_in[2];
    const float* W1    = (const float*)d_in[3];
    const float* b1    = (const float*)d_in[4];
    const float* W2    = (const float*)d_in[5];
    const float* b2    = (const float*)d_in[6];
    const float* gamma = (const float*)d_in[7];
    const float* beta  = (const float*)d_in[8];
    float* out = (float*)d_out;

    char* ws = (char*)d_ws;
    int*   counts   = (int*)(ws + WS_COUNTS);
    int*   offsets  = (int*)(ws + WS_OFFSETS);
    int*   epos     = (int*)(ws + WS_EPOS);
    int*   tok_list = (int*)(ws + WS_TOKLIST);
    float* w_list   = (float*)(ws + WS_WLIST);
    float* hbuf     = (float*)(ws + WS_HBUF);
    float* ybuf     = (float*)(ws + WS_YBUF);

    zero_counts_kernel<<<1, 64, 0, stream>>>(counts);
    gating_kernel<<<NTOK / 16, 256, 0, stream>>>(x, Wg, bg, counts, tok_list, w_list, epos);
    scan_kernel<<<1, 64, 0, stream>>>(counts, offsets);
    gemm1_kernel<<<dim3(NTOK / 128, HDIM / 64, NEXP), 256, 0, stream>>>(
        x, tok_list, counts, offsets, W1, b1, hbuf);
    gemm2_kernel<<<dim3(NTOK / 128, DDIM / 64, NEXP), 256, 0, stream>>>(
        hbuf, tok_list, w_list, counts, offsets, W2, b2, ybuf);
    ln_kernel<<<NTOK / 4, 256, 0, stream>>>(x, ybuf, epos, offsets, gamma, beta, out);
}

// Round 2
// 347.949 us; speedup vs baseline: 7.1400x; 7.1400x over previous
//
#include <hip/hip_runtime.h>
#include <math.h>

// Problem constants (B=2, S=2048 -> N=4096 tokens)
#define NTOK 4096
#define DDIM 512
#define HDIM 2048
#define NEXP 16
#define NSLOT 8192   // K=2 slots per token, always exactly 8192 total

// Workspace layout (bytes). Total ~126 MB.
#define WS_COUNTS    0u
#define WS_OFFSETS   256u
#define WS_NTILES    512u
#define WS_TILEMAP   768u        // up to 512 ints (provable bound: <=79 used)
#define WS_EPOS      4096u       // NTOK*2 ints
#define WS_TOKLIST   36864u      // NEXP*NTOK ints
#define WS_WLIST     299008u     // NEXP*NTOK floats
#define WS_XB        1048576u    // NTOK*DDIM bf16 (4 MB)
#define WS_W1T       8388608u    // [E][H][D] bf16 (33.5 MB)
#define WS_W2T       41943040u   // [E][D][H] bf16 (33.5 MB)
#define WS_HBUF      75497472u   // [NSLOT][H] bf16 (33.5 MB)
#define WS_YBUF      109051904u  // [NSLOT][D] f32  (16.8 MB)

typedef __attribute__((ext_vector_type(8))) short short8;
typedef __attribute__((ext_vector_type(4))) float floatx4;
typedef unsigned short ushort_t;

__device__ __forceinline__ ushort_t f2bf(float f) {
    unsigned u = __float_as_uint(f);
    u += 0x7fffu + ((u >> 16) & 1u);   // round-to-nearest-even
    return (ushort_t)(u >> 16);
}

// async global->LDS, 16 B per lane; LDS dest = wave-uniform base + lane*16
__device__ __forceinline__ void gload_lds16(const void* g, void* l) {
    __builtin_amdgcn_global_load_lds(
        (const __attribute__((address_space(1))) unsigned int*)g,
        (__attribute__((address_space(3))) unsigned int*)l, 16, 0, 0);
}

__global__ void zero_counts_kernel(int* __restrict__ counts) {
    if (threadIdx.x < NEXP) counts[threadIdx.x] = 0;
}

// One block = 16 tokens; thread (tl, e) computes logit[token tl][expert e]. fp32
// throughout: top-2 SELECTION must match the fp32 reference exactly.
__global__ __launch_bounds__(256) void gating_kernel(
    const float* __restrict__ x, const float* __restrict__ Wg,
    const float* __restrict__ bg, int* __restrict__ counts,
    int* __restrict__ tok_list, float* __restrict__ w_list,
    int* __restrict__ epos)
{
    const int tid = threadIdx.x;
    const int tl = tid >> 4;
    const int e  = tid & 15;
    const int t  = blockIdx.x * 16 + tl;
    const float* xr = x + (size_t)t * DDIM;

    float a0 = 0.f, a1 = 0.f, a2 = 0.f, a3 = 0.f;
    for (int d = 0; d < DDIM; d += 4) {
        a0 = fmaf(xr[d + 0], Wg[(d + 0) * NEXP + e], a0);
        a1 = fmaf(xr[d + 1], Wg[(d + 1) * NEXP + e], a1);
        a2 = fmaf(xr[d + 2], Wg[(d + 2) * NEXP + e], a2);
        a3 = fmaf(xr[d + 3], Wg[(d + 3) * NEXP + e], a3);
    }
    const float logit = (a0 + a1) + (a2 + a3) + bg[e];

    __shared__ float ls[16][16];
    ls[tl][e] = logit;
    __syncthreads();

    if (e == 0) {
        float m = -1e30f;
        #pragma unroll
        for (int j = 0; j < NEXP; ++j) m = fmaxf(m, ls[tl][j]);
        float s = 0.f;
        #pragma unroll
        for (int j = 0; j < NEXP; ++j) s += __expf(ls[tl][j] - m);
        int i0 = 0; float v0 = -1e30f;
        #pragma unroll
        for (int j = 0; j < NEXP; ++j)
            if (ls[tl][j] > v0) { v0 = ls[tl][j]; i0 = j; }
        int i1 = -1; float v1 = -1e30f;
        #pragma unroll
        for (int j = 0; j < NEXP; ++j)
            if (j != i0 && ls[tl][j] > v1) { v1 = ls[tl][j]; i1 = j; }
        const float w0 = __expf(v0 - m) / s;
        const float w1 = __expf(v1 - m) / s;

        int p0 = atomicAdd(&counts[i0], 1);
        tok_list[i0 * NTOK + p0] = t;
        w_list[i0 * NTOK + p0] = w0;
        epos[t * 2 + 0] = (i0 << 16) | p0;

        int p1 = atomicAdd(&counts[i1], 1);
        tok_list[i1 * NTOK + p1] = t;
        w_list[i1 * NTOK + p1] = w1;
        epos[t * 2 + 1] = (i1 << 16) | p1;
    }
}

// offsets prefix-scan + exact m-tile list (sum ceil(Me/128) <= 79)
__global__ void scan_kernel(const int* __restrict__ counts, int* __restrict__ offsets,
                            int* __restrict__ tilemap, int* __restrict__ ntiles)
{
    if (threadIdx.x == 0 && blockIdx.x == 0) {
        int s = 0, nt = 0;
        for (int e = 0; e < NEXP; ++e) {
            offsets[e] = s;
            const int c = counts[e];
            s += c;
            const int t = (c + 127) >> 7;
            for (int i = 0; i < t; ++i) tilemap[nt++] = (e << 16) | i;
        }
        offsets[NEXP] = s;
        *ntiles = nt;
    }
}

// x fp32 -> bf16, 8 elems/thread
__global__ __launch_bounds__(256) void cvt_x_kernel(const float* __restrict__ x,
                                                    ushort_t* __restrict__ xb)
{
    const int i = (blockIdx.x * 256 + threadIdx.x) * 8;
    const float4 v0 = *(const float4*)(x + i);
    const float4 v1 = *(const float4*)(x + i + 4);
    ushort4 a = make_ushort4(f2bf(v0.x), f2bf(v0.y), f2bf(v0.z), f2bf(v0.w));
    ushort4 b = make_ushort4(f2bf(v1.x), f2bf(v1.y), f2bf(v1.z), f2bf(v1.w));
    *(ushort4*)(xb + i) = a;
    *(ushort4*)(xb + i + 4) = b;
}

// src[z][R][C] fp32 -> dst[z][C][R] bf16 (32x32 LDS tile transpose)
__global__ __launch_bounds__(256) void transpose_cvt_kernel(
    const float* __restrict__ src, ushort_t* __restrict__ dst,
    const int R, const int C)
{
    __shared__ float tile[32][33];
    const size_t zoff = (size_t)blockIdx.z * R * C;
    const int c0 = blockIdx.x << 5;
    const int r0 = blockIdx.y << 5;
    const int ty = threadIdx.x >> 3;
    const int tx = (threadIdx.x & 7) << 2;
    const float4 v = *(const float4*)(src + zoff + (size_t)(r0 + ty) * C + c0 + tx);
    tile[ty][tx + 0] = v.x; tile[ty][tx + 1] = v.y;
    tile[ty][tx + 2] = v.z; tile[ty][tx + 3] = v.w;
    __syncthreads();
    ushort4 o = make_ushort4(f2bf(tile[tx + 0][ty]), f2bf(tile[tx + 1][ty]),
                             f2bf(tile[tx + 2][ty]), f2bf(tile[tx + 3][ty]));
    *(ushort4*)(dst + zoff + (size_t)(c0 + ty) * R + r0 + tx) = o;
}

// ---------------- MFMA GEMMs (m97 recipe: 128x128x32, global_load_lds w=16) --
// LDS tile layout [row][32 bf16] (64 B/row), k-chunk XOR-swizzled by row&3.
// Wave w owns the 64x64 quadrant (w>>1, w&1); 4x4 accs of 16x16x32 MFMA.
// A-frag: lane holds A[m=lane&15][k=(lane>>4)*8+j]; C/D: col=lane&15,
// row=(lane>>4)*4+reg  [measured: learn_hip m89].

__global__ __launch_bounds__(256) void gemm1_mfma(
    const ushort_t* __restrict__ xb, const ushort_t* __restrict__ W1t,
    const float* __restrict__ b1, const int* __restrict__ tok_list,
    const int* __restrict__ counts, const int* __restrict__ offsets,
    const int* __restrict__ tilemap, const int* __restrict__ ntiles,
    ushort_t* __restrict__ hbuf)
{
    if ((int)blockIdx.x >= *ntiles) return;
    const int tm = tilemap[blockIdx.x];
    const int e  = tm >> 16;
    const int m0 = (tm & 0xffff) << 7;
    const int Me = counts[e];
    const int aoff = offsets[e];
    const int n0 = blockIdx.y << 7;

    __shared__ __align__(16) ushort_t As[128 * 32];
    __shared__ __align__(16) ushort_t Bs[128 * 32];

    const int tid = threadIdx.x;
    const int lane = tid & 63;
    const int w = tid >> 6;

    const int row0 = (w << 4) + (lane >> 2);            // rows 0..63 (round 0)
    const int koff = ((lane & 3) ^ ((lane >> 2) & 3)) << 3;  // swizzled k-chunk

    const int tokA0 = tok_list[e * NTOK + min(m0 + row0, Me - 1)];
    const int tokA1 = tok_list[e * NTOK + min(m0 + row0 + 64, Me - 1)];
    const ushort_t* gA0 = xb + (size_t)tokA0 * DDIM + koff;
    const ushort_t* gA1 = xb + (size_t)tokA1 * DDIM + koff;
    const ushort_t* gB0 = W1t + ((size_t)e * HDIM + n0 + row0) * DDIM + koff;
    const ushort_t* gB1 = gB0 + (size_t)64 * DDIM;

    ushort_t* lA0 = As + (w << 9);           // wave-uniform LDS dests
    ushort_t* lA1 = As + 2048 + (w << 9);
    ushort_t* lB0 = Bs + (w << 9);
    ushort_t* lB1 = Bs + 2048 + (w << 9);

    const int fm = lane & 15;
    const int fq = lane >> 4;
    const int wr = (w >> 1) << 6;
    const int wc = (w & 1) << 6;
    const int fks = ((fq ^ (fm & 3)) << 3);  // swizzled frag k-offset (elems)

    floatx4 acc[4][4] = {};

    for (int k0 = 0; k0 < DDIM; k0 += 32) {
        gload_lds16(gA0 + k0, lA0);
        gload_lds16(gA1 + k0, lA1);
        gload_lds16(gB0 + k0, lB0);
        gload_lds16(gB1 + k0, lB1);
        __syncthreads();
        short8 af[4], bf[4];
        #pragma unroll
        for (int i = 0; i < 4; ++i)
            af[i] = *(const short8*)(As + ((wr + (i << 4) + fm) << 5) + fks);
        #pragma unroll
        for (int j = 0; j < 4; ++j)
            bf[j] = *(const short8*)(Bs + ((wc + (j << 4) + fm) << 5) + fks);
        #pragma unroll
        for (int i = 0; i < 4; ++i)
            #pragma unroll
            for (int j = 0; j < 4; ++j)
                acc[i][j] = __builtin_amdgcn_mfma_f32_16x16x32_bf16(
                    af[i], bf[j], acc[i][j], 0, 0, 0);
        __syncthreads();
    }

    const int er = fq << 2;
    #pragma unroll
    for (int j = 0; j < 4; ++j) {
        const int n = n0 + wc + (j << 4) + fm;
        const float bias = b1[e * HDIM + n];
        #pragma unroll
        for (int i = 0; i < 4; ++i) {
            const int mb = m0 + wr + (i << 4) + er;
            #pragma unroll
            for (int r = 0; r < 4; ++r) {
                const int m = mb + r;
                if (m < Me) {
                    const float v = fmaxf(acc[i][j][r] + bias, 0.f);
                    hbuf[(size_t)(aoff + m) * HDIM + n] = f2bf(v);
                }
            }
        }
    }
}

__global__ __launch_bounds__(256) void gemm2_mfma(
    const ushort_t* __restrict__ hbuf, const ushort_t* __restrict__ W2t,
    const float* __restrict__ b2, const float* __restrict__ w_list,
    const int* __restrict__ counts, const int* __restrict__ offsets,
    const int* __restrict__ tilemap, const int* __restrict__ ntiles,
    float* __restrict__ ybuf)
{
    if ((int)blockIdx.x >= *ntiles) return;
    const int tm = tilemap[blockIdx.x];
    const int e  = tm >> 16;
    const int m0 = (tm & 0xffff) << 7;
    const int Me = counts[e];
    const int aoff = offsets[e];
    const int n0 = blockIdx.y << 7;

    __shared__ __align__(16) ushort_t As[128 * 32];
    __shared__ __align__(16) ushort_t Bs[128 * 32];

    const int tid = threadIdx.x;
    const int lane = tid & 63;
    const int w = tid >> 6;

    const int row0 = (w << 4) + (lane >> 2);
    const int koff = ((lane & 3) ^ ((lane >> 2) & 3)) << 3;

    const int rA0 = aoff + min(m0 + row0, Me - 1);
    const int rA1 = aoff + min(m0 + row0 + 64, Me - 1);
    const ushort_t* gA0 = hbuf + (size_t)rA0 * HDIM + koff;
    const ushort_t* gA1 = hbuf + (size_t)rA1 * HDIM + koff;
    const ushort_t* gB0 = W2t + ((size_t)e * DDIM + n0 + row0) * HDIM + koff;
    const ushort_t* gB1 = gB0 + (size_t)64 * HDIM;

    ushort_t* lA0 = As + (w << 9);
    ushort_t* lA1 = As + 2048 + (w << 9);
    ushort_t* lB0 = Bs + (w << 9);
    ushort_t* lB1 = Bs + 2048 + (w << 9);

    const int fm = lane & 15;
    const int fq = lane >> 4;
    const int wr = (w >> 1) << 6;
    const int wc = (w & 1) << 6;
    const int fks = ((fq ^ (fm & 3)) << 3);

    floatx4 acc[4][4] = {};

    for (int k0 = 0; k0 < HDIM; k0 += 32) {
        gload_lds16(gA0 + k0, lA0);
        gload_lds16(gA1 + k0, lA1);
        gload_lds16(gB0 + k0, lB0);
        gload_lds16(gB1 + k0, lB1);
        __syncthreads();
        short8 af[4], bf[4];
        #pragma unroll
        for (int i = 0; i < 4; ++i)
            af[i] = *(const short8*)(As + ((wr + (i << 4) + fm) << 5) + fks);
        #pragma unroll
        for (int j = 0; j < 4; ++j)
            bf[j] = *(const short8*)(Bs + ((wc + (j << 4) + fm) << 5) + fks);
        #pragma unroll
        for (int i = 0; i < 4; ++i)
            #pragma unroll
            for (int j = 0; j < 4; ++j)
                acc[i][j] = __builtin_amdgcn_mfma_f32_16x16x32_bf16(
                    af[i], bf[j], acc[i][j], 0, 0, 0);
        __syncthreads();
    }

    const int er = fq << 2;
    #pragma unroll
    for (int j = 0; j < 4; ++j) {
        const int n = n0 + wc + (j << 4) + fm;
        const float bias = b2[e * DDIM + n];
        #pragma unroll
        for (int i = 0; i < 4; ++i) {
            const int mb = m0 + wr + (i << 4) + er;
            #pragma unroll
            for (int r = 0; r < 4; ++r) {
                const int m = mb + r;
                if (m < Me) {
                    const float gw = w_list[e * NTOK + m];
                    ybuf[(size_t)(aoff + m) * DDIM + n] =
                        gw * (acc[i][j][r] + bias);
                }
            }
        }
    }
}

// out = LayerNorm(x + y_slot0 + y_slot1) * gamma + beta; one wave per token.
__global__ __launch_bounds__(256) void ln_kernel(
    const float* __restrict__ x, const float* __restrict__ ybuf,
    const int* __restrict__ epos, const int* __restrict__ offsets,
    const float* __restrict__ gamma, const float* __restrict__ beta,
    float* __restrict__ out)
{
    const int t = blockIdx.x * 4 + (threadIdx.x >> 6);
    const int lane = threadIdx.x & 63;
    if (t >= NTOK) return;

    const int p0 = epos[2 * t + 0];
    const int p1 = epos[2 * t + 1];
    const size_t r0 = (size_t)(offsets[p0 >> 16] + (p0 & 0xFFFF));
    const size_t r1 = (size_t)(offsets[p1 >> 16] + (p1 & 0xFFFF));

    float v[8];
    float s = 0.f;
    #pragma unroll
    for (int i = 0; i < 8; ++i) {
        const int d = lane + 64 * i;
        v[i] = x[(size_t)t * DDIM + d] + ybuf[r0 * DDIM + d] + ybuf[r1 * DDIM + d];
        s += v[i];
    }
    #pragma unroll
    for (int o = 32; o > 0; o >>= 1) s += __shfl_xor(s, o, 64);
    const float mu = s * (1.f / DDIM);
    float q = 0.f;
    #pragma unroll
    for (int i = 0; i < 8; ++i) { const float d_ = v[i] - mu; q = fmaf(d_, d_, q); }
    #pragma unroll
    for (int o = 32; o > 0; o >>= 1) q += __shfl_xor(q, o, 64);
    const float rstd = rsqrtf(q * (1.f / DDIM) + 1e-5f);
    #pragma unroll
    for (int i = 0; i < 8; ++i) {
        const int d = lane + 64 * i;
        out[(size_t)t * DDIM + d] = (v[i] - mu) * rstd * gamma[d] + beta[d];
    }
}

extern "C" void kernel_launch(void* const* d_in, const int* in_sizes, int n_in,
                              void* d_out, int out_size, void* d_ws, size_t ws_size,
                              hipStream_t stream) {
    const float* x     = (const float*)d_in[0];
    const float* Wg    = (const float*)d_in[1];
    const float* bg    = (const float*)d_in[2];
    const float* W1    = (const float*)d_in[3];
    const float* b1    = (const float*)d_in[4];
    const float* W2    = (const float*)d_in[5];
    const float* b2    = (const float*)d_in[6];
    const float* gamma = (const float*)d_in[7];
    const float* beta  = (const float*)d_in[8];
    float* out = (float*)d_out;

    char* ws = (char*)d_ws;
    int*      counts   = (int*)(ws + WS_COUNTS);
    int*      offsets  = (int*)(ws + WS_OFFSETS);
    int*      ntiles   = (int*)(ws + WS_NTILES);
    int*      tilemap  = (int*)(ws + WS_TILEMAP);
    int*      epos     = (int*)(ws + WS_EPOS);
    int*      tok_list = (int*)(ws + WS_TOKLIST);
    float*    w_list   = (float*)(ws + WS_WLIST);
    ushort_t* xb       = (ushort_t*)(ws + WS_XB);
    ushort_t* W1t      = (ushort_t*)(ws + WS_W1T);
    ushort_t* W2t      = (ushort_t*)(ws + WS_W2T);
    ushort_t* hbuf     = (ushort_t*)(ws + WS_HBUF);
    float*    ybuf     = (float*)(ws + WS_YBUF);

    zero_counts_kernel<<<1, 64, 0, stream>>>(counts);
    gating_kernel<<<NTOK / 16, 256, 0, stream>>>(x, Wg, bg, counts, tok_list, w_list, epos);
    scan_kernel<<<1, 64, 0, stream>>>(counts, offsets, tilemap, ntiles);
    cvt_x_kernel<<<(NTOK * DDIM) / (256 * 8), 256, 0, stream>>>(x, xb);
    transpose_cvt_kernel<<<dim3(HDIM / 32, DDIM / 32, NEXP), 256, 0, stream>>>(W1, W1t, DDIM, HDIM);
    transpose_cvt_kernel<<<dim3(DDIM / 32, HDIM / 32, NEXP), 256, 0, stream>>>(W2, W2t, HDIM, DDIM);
    gemm1_mfma<<<dim3(80, HDIM / 128), 256, 0, stream>>>(
        xb, W1t, b1, tok_list, counts, offsets, tilemap, ntiles, hbuf);
    gemm2_mfma<<<dim3(80, DDIM / 128), 256, 0, stream>>>(
        hbuf, W2t, b2, w_list, counts, offsets, tilemap, ntiles, ybuf);
    ln_kernel<<<NTOK / 4, 256, 0, stream>>>(x, ybuf, epos, offsets, gamma, beta, out);
}